// Round 11
// baseline (312.392 us; speedup 1.0000x reference)
//
#include <hip/hip_runtime.h>
#include <math.h>

#define N_NODES 50000
#define N_EDGES 800000
#define ELL_W 64  // max in-degree ~45 for this graph (Poisson mean 16); 64 is safe

typedef __attribute__((ext_vector_type(8))) short bf16x8;
typedef __attribute__((ext_vector_type(4))) float f32x4;

__device__ __forceinline__ float leaky(float x) { return x >= 0.f ? x : 0.2f * x; }
__device__ __forceinline__ unsigned short f2bf(float f) {
  unsigned u = __float_as_uint(f);
  return (unsigned short)((u + 0x7fffu + ((u >> 16) & 1u)) >> 16);
}
__device__ __forceinline__ float bflo(unsigned u) { return __uint_as_float(u << 16); }
__device__ __forceinline__ float bfhi(unsigned u) { return __uint_as_float(u & 0xffff0000u); }
__device__ __forceinline__ unsigned pack2(float a, float b) {
  return (unsigned)f2bf(a) | ((unsigned)f2bf(b) << 16);
}

// ---------- prep: pack weights + feat->bf16 (no scatter — round 10 post-mortem) ----------
__launch_bounds__(256)
__global__ void prep_k(const float* __restrict__ feat, const float* __restrict__ W1,
                       const float* __restrict__ W2, const float* __restrict__ resW2,
                       short* __restrict__ featb, short* __restrict__ Wt1,
                       short* __restrict__ Wt2) {
  const int gtid = blockIdx.x * 256 + threadIdx.x;
  const int gsz = gridDim.x * 256;
  for (int idx = gtid; idx < 256 * 256; idx += gsz) {
    int n = idx >> 8, k = idx & 255;
    Wt1[idx] = (short)f2bf(W1[(size_t)k * 256 + n]);
  }
  for (int idx = gtid; idx < 128 * 256; idx += gsz) {
    int n = idx >> 8, k = idx & 255;
    float v = (n < 64) ? W2[(size_t)k * 64 + n] : resW2[(size_t)k * 64 + (n - 64)];
    Wt2[idx] = (short)f2bf(v);
  }
  const float4* f4 = (const float4*)feat;
  uint2* fb2 = (uint2*)featb;
  for (int idx = gtid; idx < N_NODES * 64; idx += gsz) {
    float4 f = f4[idx];
    uint2 o;
    o.x = pack2(f.x, f.y);
    o.y = pack2(f.z, f.w);
    fb2[idx] = o;
  }
}

// ---------- bf16 MFMA GEMM + fused el/er row-dot + LDS-coalesced C store ----------
// 128x128 tile, BK=32, 256 thr = 4 waves (2x2 of 64x64), 4x4 frags of 16x16x32.
// MODE 0: C -> bf16 Cb (ldc=N); each wave's 64 cols = one head -> el/er (N,4).
//         SCAT: blockIdx.y==2 strip builds the ELL adjacency, dst-PARTITIONED so
//         all writes to a node's ELL line come from one XCD (blockIdx%8 ~ XCD):
//         round 9/10 showed unpartitioned scatter costs ~47MB of cross-XCD
//         line-RMW traffic (~60us). Edge list re-read 8x = cheap streaming.
// MODE 1: N=128; cols<64 -> bf16 Cb (ld 64) + el/er (N,); cols>=64 -> fp32 Cf=acc+bias.
template <int MODE, bool SCAT>
__launch_bounds__(256)
__global__ void mfma_gemm_k(const short* __restrict__ A, const short* __restrict__ Bt,
                            const float* __restrict__ bias, const float* __restrict__ al,
                            const float* __restrict__ ar, float* __restrict__ elp,
                            float* __restrict__ erp, short* __restrict__ Cb,
                            float* __restrict__ Cf, const int* __restrict__ src,
                            const int* __restrict__ dst, int* __restrict__ cnt,
                            int* __restrict__ ell, int M, int K, int N) {
  constexpr int EPI_COLS = (MODE == 0) ? 140 : 76;
  union SharedU {
    struct { short As[4][128][8]; short Bs[4][128][8]; } ab;
    short epi[128 * EPI_COLS];
  };
  __shared__ SharedU sh;

  if (SCAT && blockIdx.y == 2) {
    const int g = blockIdx.x & 7;        // partition / XCD group
    const int bi = blockIdx.x >> 3;      // block index within group
    const int nb = (gridDim.x - g + 7) >> 3;  // blocks in this group
    const int d_lo = g * (N_NODES / 8);
    const int d_hi = (g == 7) ? N_NODES : d_lo + (N_NODES / 8);
    for (int e = bi * 256 + threadIdx.x; e < N_EDGES; e += nb * 256) {
      int d = dst[e];
      if (d >= d_lo && d < d_hi) {
        int slot = atomicAdd(cnt + d, 1);
        if (slot < ELL_W) ell[d * ELL_W + slot] = src[e];
      }
    }
    return;
  }
  const int tid = threadIdx.x;
  const int bm0 = blockIdx.x * 128, bn0 = blockIdx.y * 128;
  const int wave = tid >> 6, lane = tid & 63;
  const int wm = (wave & 1) * 64, wn = (wave >> 1) * 64;
  const int q = lane >> 4, r16 = lane & 15;
  const int srow = tid >> 1, sk = (tid & 1) * 16, sq = (tid & 1) * 2;
  f32x4 acc[4][4] = {};

  for (int k0 = 0; k0 < K; k0 += 32) {
    {
      uint4 v0 = {0, 0, 0, 0}, v1 = {0, 0, 0, 0};
      if (bm0 + srow < M) {
        const uint4* p = (const uint4*)(A + (size_t)(bm0 + srow) * K + k0 + sk);
        v0 = p[0];
        v1 = p[1];
      }
      *(uint4*)&sh.ab.As[sq][srow][0] = v0;
      *(uint4*)&sh.ab.As[sq + 1][srow][0] = v1;
    }
    {
      const uint4* p = (const uint4*)(Bt + (size_t)(bn0 + srow) * K + k0 + sk);
      *(uint4*)&sh.ab.Bs[sq][srow][0] = p[0];
      *(uint4*)&sh.ab.Bs[sq + 1][srow][0] = p[1];
    }
    __syncthreads();
    bf16x8 af[4], bfr[4];
#pragma unroll
    for (int i = 0; i < 4; ++i) af[i] = *(const bf16x8*)&sh.ab.As[q][wm + i * 16 + r16][0];
#pragma unroll
    for (int j = 0; j < 4; ++j) bfr[j] = *(const bf16x8*)&sh.ab.Bs[q][wn + j * 16 + r16][0];
#pragma unroll
    for (int i = 0; i < 4; ++i)
#pragma unroll
      for (int j = 0; j < 4; ++j)
        acc[i][j] = __builtin_amdgcn_mfma_f32_16x16x32_bf16(af[i], bfr[j], acc[i][j], 0, 0, 0);
    __syncthreads();
  }

  // fused el/er row-dot: this wave's 64 cols are exactly one head (regs only)
  if (MODE == 0 || wn == 0) {
    const int head = (bn0 + wn) >> 6;
    float alv[4], arv[4];
#pragma unroll
    for (int j = 0; j < 4; ++j) {
      alv[j] = al[((MODE == 0) ? head * 64 : 0) + j * 16 + r16];
      arv[j] = ar[((MODE == 0) ? head * 64 : 0) + j * 16 + r16];
    }
#pragma unroll
    for (int i = 0; i < 4; ++i) {
#pragma unroll
      for (int reg = 0; reg < 4; ++reg) {
        float dl = acc[i][0][reg] * alv[0] + acc[i][1][reg] * alv[1] +
                   acc[i][2][reg] * alv[2] + acc[i][3][reg] * alv[3];
        float dr = acc[i][0][reg] * arv[0] + acc[i][1][reg] * arv[1] +
                   acc[i][2][reg] * arv[2] + acc[i][3][reg] * arv[3];
#pragma unroll
        for (int mm = 1; mm < 16; mm <<= 1) {
          dl += __shfl_xor(dl, mm);
          dr += __shfl_xor(dr, mm);
        }
        int row_g = bm0 + wm + i * 16 + q * 4 + reg;
        if (r16 == 0 && row_g < M) {
          if (MODE == 0) {
            elp[(size_t)row_g * 4 + head] = dl;
            erp[(size_t)row_g * 4 + head] = dr;
          } else {
            elp[row_g] = dl;
            erp[row_g] = dr;
          }
        }
      }
    }
  }

  // ---- C store via LDS transpose -> coalesced uint4 ----
  if (MODE == 0) {
#pragma unroll
    for (int i = 0; i < 4; ++i)
#pragma unroll
      for (int reg = 0; reg < 4; ++reg) {
        int row = wm + i * 16 + q * 4 + reg;
#pragma unroll
        for (int j = 0; j < 4; ++j)
          sh.epi[row * EPI_COLS + wn + j * 16 + r16] = (short)f2bf(acc[i][j][reg]);
      }
    __syncthreads();
#pragma unroll
    for (int k = 0; k < 8; ++k) {
      int c = k * 256 + tid;          // 2048 chunks of 16B
      int row = c >> 4, cc = c & 15;  // 128 rows x 16 chunks
      int row_g = bm0 + row;
      if (row_g < M) {
        uint4 v = *(const uint4*)&sh.epi[row * EPI_COLS + cc * 8];
        *(uint4*)(Cb + (size_t)row_g * N + bn0 + cc * 8) = v;
      }
    }
  } else {
    if (wn == 0) {
#pragma unroll
      for (int i = 0; i < 4; ++i)
#pragma unroll
        for (int reg = 0; reg < 4; ++reg) {
          int row = wm + i * 16 + q * 4 + reg;
#pragma unroll
          for (int j = 0; j < 4; ++j)
            sh.epi[row * EPI_COLS + j * 16 + r16] = (short)f2bf(acc[i][j][reg]);
        }
    } else {
#pragma unroll
      for (int i = 0; i < 4; ++i)
#pragma unroll
        for (int reg = 0; reg < 4; ++reg) {
          int row_g = bm0 + wm + i * 16 + q * 4 + reg;
          if (row_g >= M) continue;
#pragma unroll
          for (int j = 0; j < 4; ++j) {
            int col = j * 16 + r16;
            Cf[(size_t)row_g * 64 + col] = acc[i][j][reg] + bias[col];
          }
        }
    }
    __syncthreads();
#pragma unroll
    for (int k = 0; k < 4; ++k) {
      int c = k * 256 + tid;         // 1024 chunks of 16B
      int row = c >> 3, cc = c & 7;  // 128 rows x 8 chunks
      int row_g = bm0 + row;
      if (row_g < M) {
        uint4 v = *(const uint4*)&sh.epi[row * EPI_COLS + cc * 8];
        *(uint4*)(Cb + (size_t)row_g * 64 + cc * 8) = v;
      }
    }
  }
}

// ---------- layer-1 softmax (no-max, |e|<~13) + aggregate + bias + ELU ----------
__launch_bounds__(256)
__global__ void agg1_k(const int* __restrict__ ell, const int* __restrict__ cnt,
                       const float* __restrict__ el, const float* __restrict__ er,
                       const short* __restrict__ ft, const float* __restrict__ bias,
                       short* __restrict__ h1) {
  int node = blockIdx.x * 4 + (threadIdx.x >> 6);
  int lane = threadIdx.x & 63;
  if (node >= N_NODES) return;
  int deg = min(cnt[node], ELL_W);
  const int* row = ell + node * ELL_W;
  int h = lane >> 4;
  float erh = er[(size_t)node * 4 + h];
  float denom = 0.f;
  float4 acc = make_float4(0.f, 0.f, 0.f, 0.f);
  int i = 0;
  for (; i + 8 <= deg; i += 8) {
    int s[8];
#pragma unroll
    for (int k = 0; k < 8; ++k) s[k] = row[i + k];
    float e[8];
    uint2 u[8];
#pragma unroll
    for (int k = 0; k < 8; ++k) e[k] = leaky(el[(size_t)s[k] * 4 + h] + erh);
#pragma unroll
    for (int k = 0; k < 8; ++k) u[k] = *(const uint2*)(ft + (size_t)s[k] * 256 + lane * 4);
    float w[8];
#pragma unroll
    for (int k = 0; k < 8; ++k) w[k] = __expf(e[k]);
#pragma unroll
    for (int k = 0; k < 8; ++k) {
      denom += w[k];
      acc.x += w[k] * bflo(u[k].x);
      acc.y += w[k] * bfhi(u[k].x);
      acc.z += w[k] * bflo(u[k].y);
      acc.w += w[k] * bfhi(u[k].y);
    }
  }
  for (; i + 4 <= deg; i += 4) {
    int s0 = row[i + 0], s1 = row[i + 1], s2 = row[i + 2], s3 = row[i + 3];
    float e0 = leaky(el[(size_t)s0 * 4 + h] + erh);
    float e1 = leaky(el[(size_t)s1 * 4 + h] + erh);
    float e2 = leaky(el[(size_t)s2 * 4 + h] + erh);
    float e3 = leaky(el[(size_t)s3 * 4 + h] + erh);
    uint2 u0 = *(const uint2*)(ft + (size_t)s0 * 256 + lane * 4);
    uint2 u1 = *(const uint2*)(ft + (size_t)s1 * 256 + lane * 4);
    uint2 u2 = *(const uint2*)(ft + (size_t)s2 * 256 + lane * 4);
    uint2 u3 = *(const uint2*)(ft + (size_t)s3 * 256 + lane * 4);
    float w0 = __expf(e0), w1 = __expf(e1), w2 = __expf(e2), w3 = __expf(e3);
    denom += (w0 + w1) + (w2 + w3);
    acc.x += (w0 * bflo(u0.x) + w1 * bflo(u1.x)) + (w2 * bflo(u2.x) + w3 * bflo(u3.x));
    acc.y += (w0 * bfhi(u0.x) + w1 * bfhi(u1.x)) + (w2 * bfhi(u2.x) + w3 * bfhi(u3.x));
    acc.z += (w0 * bflo(u0.y) + w1 * bflo(u1.y)) + (w2 * bflo(u2.y) + w3 * bflo(u3.y));
    acc.w += (w0 * bfhi(u0.y) + w1 * bfhi(u1.y)) + (w2 * bfhi(u2.y) + w3 * bfhi(u3.y));
  }
  for (; i < deg; ++i) {
    int s = row[i];
    float e = leaky(el[(size_t)s * 4 + h] + erh);
    uint2 u = *(const uint2*)(ft + (size_t)s * 256 + lane * 4);
    float w = __expf(e);
    denom += w;
    acc.x += w * bflo(u.x);
    acc.y += w * bfhi(u.x);
    acc.z += w * bflo(u.y);
    acc.w += w * bfhi(u.y);
  }
  float inv = (deg > 0) ? 1.f / denom : 0.f;
  float4 b = *(const float4*)(bias + lane * 4);
  float4 v;
  v.x = acc.x * inv + b.x;
  v.y = acc.y * inv + b.y;
  v.z = acc.z * inv + b.z;
  v.w = acc.w * inv + b.w;
  v.x = v.x > 0.f ? v.x : expm1f(v.x);
  v.y = v.y > 0.f ? v.y : expm1f(v.y);
  v.z = v.z > 0.f ? v.z : expm1f(v.z);
  v.w = v.w > 0.f ? v.w : expm1f(v.w);
  uint2 o;
  o.x = pack2(v.x, v.y);
  o.y = pack2(v.z, v.w);
  *(uint2*)(h1 + (size_t)node * 256 + lane * 4) = o;
}

// ---------- layer-2 softmax (no-max) + aggregate + residual ----------
__launch_bounds__(256)
__global__ void agg2_k(const int* __restrict__ ell, const int* __restrict__ cnt,
                       const float* __restrict__ el, const float* __restrict__ er,
                       const short* __restrict__ ft, float* __restrict__ out) {
  int node = blockIdx.x * 4 + (threadIdx.x >> 6);
  int lane = threadIdx.x & 63;
  if (node >= N_NODES) return;
  int deg = min(cnt[node], ELL_W);
  const int* row = ell + node * ELL_W;
  float erd = er[node];
  float denom = 0.f, acc = 0.f;
  int i = 0;
  for (; i + 8 <= deg; i += 8) {
    int s[8];
#pragma unroll
    for (int k = 0; k < 8; ++k) s[k] = row[i + k];
    float e[8], f[8];
#pragma unroll
    for (int k = 0; k < 8; ++k) e[k] = leaky(el[s[k]] + erd);
#pragma unroll
    for (int k = 0; k < 8; ++k)
      f[k] = bflo((unsigned)(unsigned short)ft[(size_t)s[k] * 64 + lane]);
#pragma unroll
    for (int k = 0; k < 8; ++k) {
      float w = __expf(e[k]);
      denom += w;
      acc += w * f[k];
    }
  }
  for (; i < deg; ++i) {
    int s = row[i];
    float e = leaky(el[s] + erd);
    float f = bflo((unsigned)(unsigned short)ft[(size_t)s * 64 + lane]);
    float w = __expf(e);
    denom += w;
    acc += w * f;
  }
  float r = (deg > 0) ? acc / denom : 0.f;
  out[(size_t)node * 64 + lane] += r;
}

// ---------- launch ----------
extern "C" void kernel_launch(void* const* d_in, const int* in_sizes, int n_in,
                              void* d_out, int out_size, void* d_ws, size_t ws_size,
                              hipStream_t stream) {
  const float* feat  = (const float*)d_in[0];
  const int*   src   = (const int*)d_in[1];
  const int*   dst   = (const int*)d_in[2];
  const float* W1    = (const float*)d_in[3];
  const float* al1   = (const float*)d_in[4];
  const float* ar1   = (const float*)d_in[5];
  const float* b1    = (const float*)d_in[6];
  const float* W2    = (const float*)d_in[7];
  const float* al2   = (const float*)d_in[8];
  const float* ar2   = (const float*)d_in[9];
  const float* b2    = (const float*)d_in[10];
  const float* resW2 = (const float*)d_in[11];
  float* out = (float*)d_out;

  char* p = (char*)d_ws;
  short* featb = (short*)p; p += (size_t)N_NODES * 256 * 2;
  short* ft1b = (short*)p; p += (size_t)N_NODES * 256 * 2;
  short* h1b  = (short*)p; p += (size_t)N_NODES * 256 * 2;
  short* ft2b = (short*)p; p += (size_t)N_NODES * 64 * 2;
  short* Wt1  = (short*)p; p += 256 * 256 * 2;
  short* Wt2  = (short*)p; p += 128 * 256 * 2;
  float* el1  = (float*)p; p += (size_t)N_NODES * 4 * 4;
  float* er1  = (float*)p; p += (size_t)N_NODES * 4 * 4;
  float* el2  = (float*)p; p += (size_t)N_NODES * 4;
  float* er2  = (float*)p; p += (size_t)N_NODES * 4;
  int* cnt    = (int*)p;   p += (size_t)N_NODES * 4;
  int* ell    = (int*)p;   p += (size_t)N_NODES * ELL_W * 4;

  hipMemsetAsync(cnt, 0, (size_t)N_NODES * sizeof(int), stream);

  dim3 blk(256);

  // prep: weight packs + feat->bf16
  prep_k<<<2048, blk, 0, stream>>>(feat, W1, W2, resW2, featb, Wt1, Wt2);

  // layer 1 GEMM (+fused el1/er1) with dst-partitioned ELL scatter strip (y==2)
  mfma_gemm_k<0, true><<<dim3(391, 3), blk, 0, stream>>>(
      featb, Wt1, nullptr, al1, ar1, el1, er1, ft1b, nullptr,
      src, dst, cnt, ell, N_NODES, 256, 256);
  agg1_k<<<12500, blk, 0, stream>>>(ell, cnt, el1, er1, ft1b, b1, h1b);

  // layer 2: [ft2 | res+b2] = h1 @ [W2 | resW2] + fused el2/er2
  mfma_gemm_k<1, false><<<dim3(391, 1), blk, 0, stream>>>(
      h1b, Wt2, b2, al2, ar2, el2, er2, ft2b, out,
      nullptr, nullptr, nullptr, nullptr, N_NODES, 256, 128);
  agg2_k<<<12500, blk, 0, stream>>>(ell, cnt, el2, er2, ft2b, out);
}

// Round 12
// 303.379 us; speedup vs baseline: 1.0297x; 1.0297x over previous
//
#include <hip/hip_runtime.h>
#include <math.h>

#define N_NODES 50000
#define N_EDGES 800000
#define ELL_W 64  // max in-degree ~45 for this graph (Poisson mean 16); 64 is safe

typedef __attribute__((ext_vector_type(8))) short bf16x8;
typedef __attribute__((ext_vector_type(4))) float f32x4;

__device__ __forceinline__ float leaky(float x) { return x >= 0.f ? x : 0.2f * x; }
__device__ __forceinline__ unsigned short f2bf(float f) {
  unsigned u = __float_as_uint(f);
  return (unsigned short)((u + 0x7fffu + ((u >> 16) & 1u)) >> 16);
}
__device__ __forceinline__ float bflo(unsigned u) { return __uint_as_float(u << 16); }
__device__ __forceinline__ float bfhi(unsigned u) { return __uint_as_float(u & 0xffff0000u); }
__device__ __forceinline__ unsigned pack2(float a, float b) {
  return (unsigned)f2bf(a) | ((unsigned)f2bf(b) << 16);
}

// ---------- prep: pack weights + feat->bf16 + zero cnt (replaces memset) ----------
__launch_bounds__(256)
__global__ void prep_k(const float* __restrict__ feat, const float* __restrict__ W1,
                       const float* __restrict__ W2, const float* __restrict__ resW2,
                       short* __restrict__ featb, short* __restrict__ Wt1,
                       short* __restrict__ Wt2, int* __restrict__ cnt) {
  const int gtid = blockIdx.x * 256 + threadIdx.x;
  const int gsz = gridDim.x * 256;
  for (int i = gtid; i < N_NODES; i += gsz) cnt[i] = 0;
  for (int idx = gtid; idx < 256 * 256; idx += gsz) {
    int n = idx >> 8, k = idx & 255;
    Wt1[idx] = (short)f2bf(W1[(size_t)k * 256 + n]);
  }
  for (int idx = gtid; idx < 128 * 256; idx += gsz) {
    int n = idx >> 8, k = idx & 255;
    float v = (n < 64) ? W2[(size_t)k * 64 + n] : resW2[(size_t)k * 64 + (n - 64)];
    Wt2[idx] = (short)f2bf(v);
  }
  const float4* f4 = (const float4*)feat;
  uint2* fb2 = (uint2*)featb;
  for (int idx = gtid; idx < N_NODES * 64; idx += gsz) {
    float4 f = f4[idx];
    uint2 o;
    o.x = pack2(f.x, f.y);
    o.y = pack2(f.z, f.w);
    fb2[idx] = o;
  }
}

// ---------- bf16 MFMA GEMM + fused el/er row-dot + LDS-coalesced C store ----------
// 128x128 tile, BK=32, 256 thr = 4 waves (2x2 of 64x64), 4x4 frags of 16x16x32.
// MODE 0: C -> bf16 Cb (ldc=N); each wave's 64 cols = one head -> el/er (N,4).
//         SCAT: blockIdx.y==2 strip builds the ushort ELL via NONTEMPORAL stores
//         (rounds 8-11: write-allocate line RMW on random 4B stores cost ~45MB
//         of extra HBM traffic; nt store bypasses L2 allocation entirely).
// MODE 1: N=128; cols<64 -> bf16 Cb (ld 64) + el/er (N,); cols>=64 -> fp32 Cf=acc+bias.
template <int MODE, bool SCAT>
__launch_bounds__(256)
__global__ void mfma_gemm_k(const short* __restrict__ A, const short* __restrict__ Bt,
                            const float* __restrict__ bias, const float* __restrict__ al,
                            const float* __restrict__ ar, float* __restrict__ elp,
                            float* __restrict__ erp, short* __restrict__ Cb,
                            float* __restrict__ Cf, const int* __restrict__ src,
                            const int* __restrict__ dst, int* __restrict__ cnt,
                            unsigned short* __restrict__ ell, int M, int K, int N) {
  constexpr int EPI_COLS = (MODE == 0) ? 140 : 76;
  union SharedU {
    struct { short As[4][128][8]; short Bs[4][128][8]; } ab;
    short epi[128 * EPI_COLS];
  };
  __shared__ SharedU sh;

  if (SCAT && blockIdx.y == 2) {
    const int gtid = blockIdx.x * 256 + threadIdx.x;
    const int gsz = gridDim.x * 256;
    for (int e = gtid; e < N_EDGES; e += gsz) {
      int d = dst[e];
      int slot = atomicAdd(cnt + d, 1);
      if (slot < ELL_W)
        __builtin_nontemporal_store((unsigned short)src[e],
                                    ell + (size_t)d * ELL_W + slot);
    }
    return;
  }
  const int tid = threadIdx.x;
  const int bm0 = blockIdx.x * 128, bn0 = blockIdx.y * 128;
  const int wave = tid >> 6, lane = tid & 63;
  const int wm = (wave & 1) * 64, wn = (wave >> 1) * 64;
  const int q = lane >> 4, r16 = lane & 15;
  const int srow = tid >> 1, sk = (tid & 1) * 16, sq = (tid & 1) * 2;
  f32x4 acc[4][4] = {};

  for (int k0 = 0; k0 < K; k0 += 32) {
    {
      uint4 v0 = {0, 0, 0, 0}, v1 = {0, 0, 0, 0};
      if (bm0 + srow < M) {
        const uint4* p = (const uint4*)(A + (size_t)(bm0 + srow) * K + k0 + sk);
        v0 = p[0];
        v1 = p[1];
      }
      *(uint4*)&sh.ab.As[sq][srow][0] = v0;
      *(uint4*)&sh.ab.As[sq + 1][srow][0] = v1;
    }
    {
      const uint4* p = (const uint4*)(Bt + (size_t)(bn0 + srow) * K + k0 + sk);
      *(uint4*)&sh.ab.Bs[sq][srow][0] = p[0];
      *(uint4*)&sh.ab.Bs[sq + 1][srow][0] = p[1];
    }
    __syncthreads();
    bf16x8 af[4], bfr[4];
#pragma unroll
    for (int i = 0; i < 4; ++i) af[i] = *(const bf16x8*)&sh.ab.As[q][wm + i * 16 + r16][0];
#pragma unroll
    for (int j = 0; j < 4; ++j) bfr[j] = *(const bf16x8*)&sh.ab.Bs[q][wn + j * 16 + r16][0];
#pragma unroll
    for (int i = 0; i < 4; ++i)
#pragma unroll
      for (int j = 0; j < 4; ++j)
        acc[i][j] = __builtin_amdgcn_mfma_f32_16x16x32_bf16(af[i], bfr[j], acc[i][j], 0, 0, 0);
    __syncthreads();
  }

  // fused el/er row-dot: this wave's 64 cols are exactly one head (regs only)
  if (MODE == 0 || wn == 0) {
    const int head = (bn0 + wn) >> 6;
    float alv[4], arv[4];
#pragma unroll
    for (int j = 0; j < 4; ++j) {
      alv[j] = al[((MODE == 0) ? head * 64 : 0) + j * 16 + r16];
      arv[j] = ar[((MODE == 0) ? head * 64 : 0) + j * 16 + r16];
    }
#pragma unroll
    for (int i = 0; i < 4; ++i) {
#pragma unroll
      for (int reg = 0; reg < 4; ++reg) {
        float dl = acc[i][0][reg] * alv[0] + acc[i][1][reg] * alv[1] +
                   acc[i][2][reg] * alv[2] + acc[i][3][reg] * alv[3];
        float dr = acc[i][0][reg] * arv[0] + acc[i][1][reg] * arv[1] +
                   acc[i][2][reg] * arv[2] + acc[i][3][reg] * arv[3];
#pragma unroll
        for (int mm = 1; mm < 16; mm <<= 1) {
          dl += __shfl_xor(dl, mm);
          dr += __shfl_xor(dr, mm);
        }
        int row_g = bm0 + wm + i * 16 + q * 4 + reg;
        if (r16 == 0 && row_g < M) {
          if (MODE == 0) {
            elp[(size_t)row_g * 4 + head] = dl;
            erp[(size_t)row_g * 4 + head] = dr;
          } else {
            elp[row_g] = dl;
            erp[row_g] = dr;
          }
        }
      }
    }
  }

  // ---- C store via LDS transpose -> coalesced uint4 ----
  if (MODE == 0) {
#pragma unroll
    for (int i = 0; i < 4; ++i)
#pragma unroll
      for (int reg = 0; reg < 4; ++reg) {
        int row = wm + i * 16 + q * 4 + reg;
#pragma unroll
        for (int j = 0; j < 4; ++j)
          sh.epi[row * EPI_COLS + wn + j * 16 + r16] = (short)f2bf(acc[i][j][reg]);
      }
    __syncthreads();
#pragma unroll
    for (int k = 0; k < 8; ++k) {
      int c = k * 256 + tid;          // 2048 chunks of 16B
      int row = c >> 4, cc = c & 15;  // 128 rows x 16 chunks
      int row_g = bm0 + row;
      if (row_g < M) {
        uint4 v = *(const uint4*)&sh.epi[row * EPI_COLS + cc * 8];
        *(uint4*)(Cb + (size_t)row_g * N + bn0 + cc * 8) = v;
      }
    }
  } else {
    if (wn == 0) {
#pragma unroll
      for (int i = 0; i < 4; ++i)
#pragma unroll
        for (int reg = 0; reg < 4; ++reg) {
          int row = wm + i * 16 + q * 4 + reg;
#pragma unroll
          for (int j = 0; j < 4; ++j)
            sh.epi[row * EPI_COLS + j * 16 + r16] = (short)f2bf(acc[i][j][reg]);
        }
    } else {
#pragma unroll
      for (int i = 0; i < 4; ++i)
#pragma unroll
        for (int reg = 0; reg < 4; ++reg) {
          int row_g = bm0 + wm + i * 16 + q * 4 + reg;
          if (row_g >= M) continue;
#pragma unroll
          for (int j = 0; j < 4; ++j) {
            int col = j * 16 + r16;
            Cf[(size_t)row_g * 64 + col] = acc[i][j][reg] + bias[col];
          }
        }
    }
    __syncthreads();
#pragma unroll
    for (int k = 0; k < 4; ++k) {
      int c = k * 256 + tid;         // 1024 chunks of 16B
      int row = c >> 3, cc = c & 7;  // 128 rows x 8 chunks
      int row_g = bm0 + row;
      if (row_g < M) {
        uint4 v = *(const uint4*)&sh.epi[row * EPI_COLS + cc * 8];
        *(uint4*)(Cb + (size_t)row_g * 64 + cc * 8) = v;
      }
    }
  }
}

// ---------- layer-1 softmax (no-max, |e|<~13) + aggregate + bias + ELU ----------
__launch_bounds__(256)
__global__ void agg1_k(const unsigned short* __restrict__ ell, const int* __restrict__ cnt,
                       const float* __restrict__ el, const float* __restrict__ er,
                       const short* __restrict__ ft, const float* __restrict__ bias,
                       short* __restrict__ h1) {
  int node = blockIdx.x * 4 + (threadIdx.x >> 6);
  int lane = threadIdx.x & 63;
  if (node >= N_NODES) return;
  int deg = min(cnt[node], ELL_W);
  const unsigned short* row = ell + (size_t)node * ELL_W;
  int h = lane >> 4;
  float erh = er[(size_t)node * 4 + h];
  float denom = 0.f;
  float4 acc = make_float4(0.f, 0.f, 0.f, 0.f);
  int i = 0;
  for (; i + 8 <= deg; i += 8) {
    int s[8];
#pragma unroll
    for (int k = 0; k < 8; ++k) s[k] = row[i + k];
    float e[8];
    uint2 u[8];
#pragma unroll
    for (int k = 0; k < 8; ++k) e[k] = leaky(el[(size_t)s[k] * 4 + h] + erh);
#pragma unroll
    for (int k = 0; k < 8; ++k) u[k] = *(const uint2*)(ft + (size_t)s[k] * 256 + lane * 4);
    float w[8];
#pragma unroll
    for (int k = 0; k < 8; ++k) w[k] = __expf(e[k]);
#pragma unroll
    for (int k = 0; k < 8; ++k) {
      denom += w[k];
      acc.x += w[k] * bflo(u[k].x);
      acc.y += w[k] * bfhi(u[k].x);
      acc.z += w[k] * bflo(u[k].y);
      acc.w += w[k] * bfhi(u[k].y);
    }
  }
  for (; i + 4 <= deg; i += 4) {
    int s0 = row[i + 0], s1 = row[i + 1], s2 = row[i + 2], s3 = row[i + 3];
    float e0 = leaky(el[(size_t)s0 * 4 + h] + erh);
    float e1 = leaky(el[(size_t)s1 * 4 + h] + erh);
    float e2 = leaky(el[(size_t)s2 * 4 + h] + erh);
    float e3 = leaky(el[(size_t)s3 * 4 + h] + erh);
    uint2 u0 = *(const uint2*)(ft + (size_t)s0 * 256 + lane * 4);
    uint2 u1 = *(const uint2*)(ft + (size_t)s1 * 256 + lane * 4);
    uint2 u2 = *(const uint2*)(ft + (size_t)s2 * 256 + lane * 4);
    uint2 u3 = *(const uint2*)(ft + (size_t)s3 * 256 + lane * 4);
    float w0 = __expf(e0), w1 = __expf(e1), w2 = __expf(e2), w3 = __expf(e3);
    denom += (w0 + w1) + (w2 + w3);
    acc.x += (w0 * bflo(u0.x) + w1 * bflo(u1.x)) + (w2 * bflo(u2.x) + w3 * bflo(u3.x));
    acc.y += (w0 * bfhi(u0.x) + w1 * bfhi(u1.x)) + (w2 * bfhi(u2.x) + w3 * bfhi(u3.x));
    acc.z += (w0 * bflo(u0.y) + w1 * bflo(u1.y)) + (w2 * bflo(u2.y) + w3 * bflo(u3.y));
    acc.w += (w0 * bfhi(u0.y) + w1 * bfhi(u1.y)) + (w2 * bfhi(u2.y) + w3 * bfhi(u3.y));
  }
  for (; i < deg; ++i) {
    int s = row[i];
    float e = leaky(el[(size_t)s * 4 + h] + erh);
    uint2 u = *(const uint2*)(ft + (size_t)s * 256 + lane * 4);
    float w = __expf(e);
    denom += w;
    acc.x += w * bflo(u.x);
    acc.y += w * bfhi(u.x);
    acc.z += w * bflo(u.y);
    acc.w += w * bfhi(u.y);
  }
  float inv = (deg > 0) ? 1.f / denom : 0.f;
  float4 b = *(const float4*)(bias + lane * 4);
  float4 v;
  v.x = acc.x * inv + b.x;
  v.y = acc.y * inv + b.y;
  v.z = acc.z * inv + b.z;
  v.w = acc.w * inv + b.w;
  v.x = v.x > 0.f ? v.x : expm1f(v.x);
  v.y = v.y > 0.f ? v.y : expm1f(v.y);
  v.z = v.z > 0.f ? v.z : expm1f(v.z);
  v.w = v.w > 0.f ? v.w : expm1f(v.w);
  uint2 o;
  o.x = pack2(v.x, v.y);
  o.y = pack2(v.z, v.w);
  *(uint2*)(h1 + (size_t)node * 256 + lane * 4) = o;
}

// ---------- layer-2 softmax (no-max) + aggregate + residual ----------
__launch_bounds__(256)
__global__ void agg2_k(const unsigned short* __restrict__ ell, const int* __restrict__ cnt,
                       const float* __restrict__ el, const float* __restrict__ er,
                       const short* __restrict__ ft, float* __restrict__ out) {
  int node = blockIdx.x * 4 + (threadIdx.x >> 6);
  int lane = threadIdx.x & 63;
  if (node >= N_NODES) return;
  int deg = min(cnt[node], ELL_W);
  const unsigned short* row = ell + (size_t)node * ELL_W;
  float erd = er[node];
  float denom = 0.f, acc = 0.f;
  int i = 0;
  for (; i + 8 <= deg; i += 8) {
    int s[8];
#pragma unroll
    for (int k = 0; k < 8; ++k) s[k] = row[i + k];
    float e[8], f[8];
#pragma unroll
    for (int k = 0; k < 8; ++k) e[k] = leaky(el[s[k]] + erd);
#pragma unroll
    for (int k = 0; k < 8; ++k)
      f[k] = bflo((unsigned)(unsigned short)ft[(size_t)s[k] * 64 + lane]);
#pragma unroll
    for (int k = 0; k < 8; ++k) {
      float w = __expf(e[k]);
      denom += w;
      acc += w * f[k];
    }
  }
  for (; i < deg; ++i) {
    int s = row[i];
    float e = leaky(el[s] + erd);
    float f = bflo((unsigned)(unsigned short)ft[(size_t)s * 64 + lane]);
    float w = __expf(e);
    denom += w;
    acc += w * f;
  }
  float r = (deg > 0) ? acc / denom : 0.f;
  out[(size_t)node * 64 + lane] += r;
}

// ---------- launch ----------
extern "C" void kernel_launch(void* const* d_in, const int* in_sizes, int n_in,
                              void* d_out, int out_size, void* d_ws, size_t ws_size,
                              hipStream_t stream) {
  const float* feat  = (const float*)d_in[0];
  const int*   src   = (const int*)d_in[1];
  const int*   dst   = (const int*)d_in[2];
  const float* W1    = (const float*)d_in[3];
  const float* al1   = (const float*)d_in[4];
  const float* ar1   = (const float*)d_in[5];
  const float* b1    = (const float*)d_in[6];
  const float* W2    = (const float*)d_in[7];
  const float* al2   = (const float*)d_in[8];
  const float* ar2   = (const float*)d_in[9];
  const float* b2    = (const float*)d_in[10];
  const float* resW2 = (const float*)d_in[11];
  float* out = (float*)d_out;

  char* p = (char*)d_ws;
  short* featb = (short*)p; p += (size_t)N_NODES * 256 * 2;
  short* ft1b = (short*)p; p += (size_t)N_NODES * 256 * 2;
  short* h1b  = (short*)p; p += (size_t)N_NODES * 256 * 2;
  short* ft2b = (short*)p; p += (size_t)N_NODES * 64 * 2;
  short* Wt1  = (short*)p; p += 256 * 256 * 2;
  short* Wt2  = (short*)p; p += 128 * 256 * 2;
  float* el1  = (float*)p; p += (size_t)N_NODES * 4 * 4;
  float* er1  = (float*)p; p += (size_t)N_NODES * 4 * 4;
  float* el2  = (float*)p; p += (size_t)N_NODES * 4;
  float* er2  = (float*)p; p += (size_t)N_NODES * 4;
  int* cnt    = (int*)p;   p += (size_t)N_NODES * 4;
  unsigned short* ell = (unsigned short*)p;  // 50000*64*2 = 6.4MB

  dim3 blk(256);

  // prep: weight packs + feat->bf16 + cnt zero (memset dispatch eliminated)
  prep_k<<<2048, blk, 0, stream>>>(feat, W1, W2, resW2, featb, Wt1, Wt2, cnt);

  // layer 1 GEMM (+fused el1/er1) with nt-store ELL scatter strip (y==2)
  mfma_gemm_k<0, true><<<dim3(391, 3), blk, 0, stream>>>(
      featb, Wt1, nullptr, al1, ar1, el1, er1, ft1b, nullptr,
      src, dst, cnt, ell, N_NODES, 256, 256);
  agg1_k<<<12500, blk, 0, stream>>>(ell, cnt, el1, er1, ft1b, b1, h1b);

  // layer 2: [ft2 | res+b2] = h1 @ [W2 | resW2] + fused el2/er2
  mfma_gemm_k<1, false><<<dim3(391, 1), blk, 0, stream>>>(
      h1b, Wt2, b2, al2, ar2, el2, er2, ft2b, out,
      nullptr, nullptr, nullptr, nullptr, N_NODES, 256, 128);
  agg2_k<<<12500, blk, 0, stream>>>(ell, cnt, el2, er2, ft2b, out);
}

// Round 13
// 293.602 us; speedup vs baseline: 1.0640x; 1.0333x over previous
//
#include <hip/hip_runtime.h>
#include <math.h>

#define N_NODES 50000
#define N_EDGES 800000
#define ELL_W 64  // max in-degree ~45 for this graph (Poisson mean 16); 64 is safe

typedef __attribute__((ext_vector_type(8))) short bf16x8;
typedef __attribute__((ext_vector_type(4))) float f32x4;

__device__ __forceinline__ float leaky(float x) { return x >= 0.f ? x : 0.2f * x; }
__device__ __forceinline__ unsigned short f2bf(float f) {
  unsigned u = __float_as_uint(f);
  return (unsigned short)((u + 0x7fffu + ((u >> 16) & 1u)) >> 16);
}
__device__ __forceinline__ float bflo(unsigned u) { return __uint_as_float(u << 16); }
__device__ __forceinline__ float bfhi(unsigned u) { return __uint_as_float(u & 0xffff0000u); }
__device__ __forceinline__ unsigned pack2(float a, float b) {
  return (unsigned)f2bf(a) | ((unsigned)f2bf(b) << 16);
}

// ---------- prep: pack weights + slot assignment (cnt pre-zeroed by memset) ----------
// The atomics live HERE, overlapped with streaming weight packs; the GEMM strip
// then does atomic-free stores (round 12: atomic+store in the strip was the stall).
__launch_bounds__(256)
__global__ void prep_k(const float* __restrict__ W1, const float* __restrict__ W2,
                       const float* __restrict__ resW2, const int* __restrict__ dst,
                       short* __restrict__ Wt1, short* __restrict__ Wt2,
                       int* __restrict__ cnt, unsigned char* __restrict__ slot8) {
  const int gtid = blockIdx.x * 256 + threadIdx.x;
  const int gsz = gridDim.x * 256;
  for (int idx = gtid; idx < 256 * 256; idx += gsz) {
    int n = idx >> 8, k = idx & 255;
    Wt1[idx] = (short)f2bf(W1[(size_t)k * 256 + n]);
  }
  for (int idx = gtid; idx < 128 * 256; idx += gsz) {
    int n = idx >> 8, k = idx & 255;
    float v = (n < 64) ? W2[(size_t)k * 64 + n] : resW2[(size_t)k * 64 + (n - 64)];
    Wt2[idx] = (short)f2bf(v);
  }
  for (int e = gtid; e < N_EDGES; e += gsz) {
    int s = atomicAdd(cnt + dst[e], 1);
    slot8[e] = (unsigned char)min(s, 255);
  }
}

// ---------- bf16 MFMA GEMM + fused el/er row-dot + LDS-coalesced C store ----------
// 128x128 tile, BK=32, 256 thr = 4 waves (2x2 of 64x64), 4x4 frags of 16x16x32.
// MODE 0: A is fp32 (packed to bf16 during staging); C -> bf16 Cb (ldc=N);
//         each wave's 64 cols = one head -> el/er (N,4).
//         SCAT: blockIdx.y==2 strip fills ELL with PRE-ASSIGNED slots (pure
//         stores, no atomics — slot array computed in prep).
// MODE 1: A bf16; N=128; cols<64 -> bf16 Cb (ld 64) + el/er (N,); cols>=64 ->
//         fp32 Cf = acc + bias[col-64].
template <int MODE, bool SCAT>
__launch_bounds__(256)
__global__ void mfma_gemm_k(const void* __restrict__ Ap, const short* __restrict__ Bt,
                            const float* __restrict__ bias, const float* __restrict__ al,
                            const float* __restrict__ ar, float* __restrict__ elp,
                            float* __restrict__ erp, short* __restrict__ Cb,
                            float* __restrict__ Cf, const int* __restrict__ src,
                            const int* __restrict__ dst,
                            const unsigned char* __restrict__ slot8,
                            int* __restrict__ ell, int M, int K, int N) {
  constexpr int EPI_COLS = (MODE == 0) ? 140 : 76;
  union SharedU {
    struct { short As[4][128][8]; short Bs[4][128][8]; } ab;
    short epi[128 * EPI_COLS];
  };
  __shared__ SharedU sh;

  if (SCAT && blockIdx.y == 2) {
    const int gtid = blockIdx.x * 256 + threadIdx.x;
    const int gsz = gridDim.x * 256;
    for (int e = gtid; e < N_EDGES; e += gsz) {
      int slot = slot8[e];
      if (slot < ELL_W) ell[(size_t)dst[e] * ELL_W + slot] = src[e];
    }
    return;
  }
  const int tid = threadIdx.x;
  const int bm0 = blockIdx.x * 128, bn0 = blockIdx.y * 128;
  const int wave = tid >> 6, lane = tid & 63;
  const int wm = (wave & 1) * 64, wn = (wave >> 1) * 64;
  const int q = lane >> 4, r16 = lane & 15;
  const int srow = tid >> 1, sk = (tid & 1) * 16, sq = (tid & 1) * 2;
  f32x4 acc[4][4] = {};

  for (int k0 = 0; k0 < K; k0 += 32) {
    if (MODE == 0) {
      // fp32 A: read 16 floats, pack to bf16 in-flight (featb buffer eliminated)
      const float* A = (const float*)Ap;
      float4 f0 = {0, 0, 0, 0}, f1 = f0, f2 = f0, f3 = f0;
      if (bm0 + srow < M) {
        const float4* p = (const float4*)(A + (size_t)(bm0 + srow) * K + k0 + sk);
        f0 = p[0];
        f1 = p[1];
        f2 = p[2];
        f3 = p[3];
      }
      uint4 v0, v1;
      v0.x = pack2(f0.x, f0.y); v0.y = pack2(f0.z, f0.w);
      v0.z = pack2(f1.x, f1.y); v0.w = pack2(f1.z, f1.w);
      v1.x = pack2(f2.x, f2.y); v1.y = pack2(f2.z, f2.w);
      v1.z = pack2(f3.x, f3.y); v1.w = pack2(f3.z, f3.w);
      *(uint4*)&sh.ab.As[sq][srow][0] = v0;
      *(uint4*)&sh.ab.As[sq + 1][srow][0] = v1;
    } else {
      const short* A = (const short*)Ap;
      uint4 v0 = {0, 0, 0, 0}, v1 = {0, 0, 0, 0};
      if (bm0 + srow < M) {
        const uint4* p = (const uint4*)(A + (size_t)(bm0 + srow) * K + k0 + sk);
        v0 = p[0];
        v1 = p[1];
      }
      *(uint4*)&sh.ab.As[sq][srow][0] = v0;
      *(uint4*)&sh.ab.As[sq + 1][srow][0] = v1;
    }
    {
      const uint4* p = (const uint4*)(Bt + (size_t)(bn0 + srow) * K + k0 + sk);
      *(uint4*)&sh.ab.Bs[sq][srow][0] = p[0];
      *(uint4*)&sh.ab.Bs[sq + 1][srow][0] = p[1];
    }
    __syncthreads();
    bf16x8 af[4], bfr[4];
#pragma unroll
    for (int i = 0; i < 4; ++i) af[i] = *(const bf16x8*)&sh.ab.As[q][wm + i * 16 + r16][0];
#pragma unroll
    for (int j = 0; j < 4; ++j) bfr[j] = *(const bf16x8*)&sh.ab.Bs[q][wn + j * 16 + r16][0];
#pragma unroll
    for (int i = 0; i < 4; ++i)
#pragma unroll
      for (int j = 0; j < 4; ++j)
        acc[i][j] = __builtin_amdgcn_mfma_f32_16x16x32_bf16(af[i], bfr[j], acc[i][j], 0, 0, 0);
    __syncthreads();
  }

  // fused el/er row-dot: this wave's 64 cols are exactly one head (regs only)
  if (MODE == 0 || wn == 0) {
    const int head = (bn0 + wn) >> 6;
    float alv[4], arv[4];
#pragma unroll
    for (int j = 0; j < 4; ++j) {
      alv[j] = al[((MODE == 0) ? head * 64 : 0) + j * 16 + r16];
      arv[j] = ar[((MODE == 0) ? head * 64 : 0) + j * 16 + r16];
    }
#pragma unroll
    for (int i = 0; i < 4; ++i) {
#pragma unroll
      for (int reg = 0; reg < 4; ++reg) {
        float dl = acc[i][0][reg] * alv[0] + acc[i][1][reg] * alv[1] +
                   acc[i][2][reg] * alv[2] + acc[i][3][reg] * alv[3];
        float dr = acc[i][0][reg] * arv[0] + acc[i][1][reg] * arv[1] +
                   acc[i][2][reg] * arv[2] + acc[i][3][reg] * arv[3];
#pragma unroll
        for (int mm = 1; mm < 16; mm <<= 1) {
          dl += __shfl_xor(dl, mm);
          dr += __shfl_xor(dr, mm);
        }
        int row_g = bm0 + wm + i * 16 + q * 4 + reg;
        if (r16 == 0 && row_g < M) {
          if (MODE == 0) {
            elp[(size_t)row_g * 4 + head] = dl;
            erp[(size_t)row_g * 4 + head] = dr;
          } else {
            elp[row_g] = dl;
            erp[row_g] = dr;
          }
        }
      }
    }
  }

  // ---- C store via LDS transpose -> coalesced uint4 ----
  if (MODE == 0) {
#pragma unroll
    for (int i = 0; i < 4; ++i)
#pragma unroll
      for (int reg = 0; reg < 4; ++reg) {
        int row = wm + i * 16 + q * 4 + reg;
#pragma unroll
        for (int j = 0; j < 4; ++j)
          sh.epi[row * EPI_COLS + wn + j * 16 + r16] = (short)f2bf(acc[i][j][reg]);
      }
    __syncthreads();
#pragma unroll
    for (int k = 0; k < 8; ++k) {
      int c = k * 256 + tid;          // 2048 chunks of 16B
      int row = c >> 4, cc = c & 15;  // 128 rows x 16 chunks
      int row_g = bm0 + row;
      if (row_g < M) {
        uint4 v = *(const uint4*)&sh.epi[row * EPI_COLS + cc * 8];
        *(uint4*)(Cb + (size_t)row_g * N + bn0 + cc * 8) = v;
      }
    }
  } else {
    if (wn == 0) {
#pragma unroll
      for (int i = 0; i < 4; ++i)
#pragma unroll
        for (int reg = 0; reg < 4; ++reg) {
          int row = wm + i * 16 + q * 4 + reg;
#pragma unroll
          for (int j = 0; j < 4; ++j)
            sh.epi[row * EPI_COLS + j * 16 + r16] = (short)f2bf(acc[i][j][reg]);
        }
    } else {
#pragma unroll
      for (int i = 0; i < 4; ++i)
#pragma unroll
        for (int reg = 0; reg < 4; ++reg) {
          int row_g = bm0 + wm + i * 16 + q * 4 + reg;
          if (row_g >= M) continue;
#pragma unroll
          for (int j = 0; j < 4; ++j) {
            int col = j * 16 + r16;
            Cf[(size_t)row_g * 64 + col] = acc[i][j][reg] + bias[col];
          }
        }
    }
    __syncthreads();
#pragma unroll
    for (int k = 0; k < 4; ++k) {
      int c = k * 256 + tid;         // 1024 chunks of 16B
      int row = c >> 3, cc = c & 7;  // 128 rows x 8 chunks
      int row_g = bm0 + row;
      if (row_g < M) {
        uint4 v = *(const uint4*)&sh.epi[row * EPI_COLS + cc * 8];
        *(uint4*)(Cb + (size_t)row_g * 64 + cc * 8) = v;
      }
    }
  }
}

// ---------- layer-1 softmax (no-max, |e|<~13) + aggregate + bias + ELU ----------
__launch_bounds__(256)
__global__ void agg1_k(const int* __restrict__ ell, const int* __restrict__ cnt,
                       const float* __restrict__ el, const float* __restrict__ er,
                       const short* __restrict__ ft, const float* __restrict__ bias,
                       short* __restrict__ h1) {
  int node = blockIdx.x * 4 + (threadIdx.x >> 6);
  int lane = threadIdx.x & 63;
  if (node >= N_NODES) return;
  int deg = min(cnt[node], ELL_W);
  const int* row = ell + (size_t)node * ELL_W;
  int h = lane >> 4;
  float erh = er[(size_t)node * 4 + h];
  float denom = 0.f;
  float4 acc = make_float4(0.f, 0.f, 0.f, 0.f);
  int i = 0;
  for (; i + 8 <= deg; i += 8) {
    int s[8];
#pragma unroll
    for (int k = 0; k < 8; ++k) s[k] = row[i + k];
    float e[8];
    uint2 u[8];
#pragma unroll
    for (int k = 0; k < 8; ++k) e[k] = leaky(el[(size_t)s[k] * 4 + h] + erh);
#pragma unroll
    for (int k = 0; k < 8; ++k) u[k] = *(const uint2*)(ft + (size_t)s[k] * 256 + lane * 4);
    float w[8];
#pragma unroll
    for (int k = 0; k < 8; ++k) w[k] = __expf(e[k]);
#pragma unroll
    for (int k = 0; k < 8; ++k) {
      denom += w[k];
      acc.x += w[k] * bflo(u[k].x);
      acc.y += w[k] * bfhi(u[k].x);
      acc.z += w[k] * bflo(u[k].y);
      acc.w += w[k] * bfhi(u[k].y);
    }
  }
  for (; i + 4 <= deg; i += 4) {
    int s0 = row[i + 0], s1 = row[i + 1], s2 = row[i + 2], s3 = row[i + 3];
    float e0 = leaky(el[(size_t)s0 * 4 + h] + erh);
    float e1 = leaky(el[(size_t)s1 * 4 + h] + erh);
    float e2 = leaky(el[(size_t)s2 * 4 + h] + erh);
    float e3 = leaky(el[(size_t)s3 * 4 + h] + erh);
    uint2 u0 = *(const uint2*)(ft + (size_t)s0 * 256 + lane * 4);
    uint2 u1 = *(const uint2*)(ft + (size_t)s1 * 256 + lane * 4);
    uint2 u2 = *(const uint2*)(ft + (size_t)s2 * 256 + lane * 4);
    uint2 u3 = *(const uint2*)(ft + (size_t)s3 * 256 + lane * 4);
    float w0 = __expf(e0), w1 = __expf(e1), w2 = __expf(e2), w3 = __expf(e3);
    denom += (w0 + w1) + (w2 + w3);
    acc.x += (w0 * bflo(u0.x) + w1 * bflo(u1.x)) + (w2 * bflo(u2.x) + w3 * bflo(u3.x));
    acc.y += (w0 * bfhi(u0.x) + w1 * bfhi(u1.x)) + (w2 * bfhi(u2.x) + w3 * bfhi(u3.x));
    acc.z += (w0 * bflo(u0.y) + w1 * bflo(u1.y)) + (w2 * bflo(u2.y) + w3 * bflo(u3.y));
    acc.w += (w0 * bfhi(u0.y) + w1 * bfhi(u1.y)) + (w2 * bfhi(u2.y) + w3 * bfhi(u3.y));
  }
  for (; i < deg; ++i) {
    int s = row[i];
    float e = leaky(el[(size_t)s * 4 + h] + erh);
    uint2 u = *(const uint2*)(ft + (size_t)s * 256 + lane * 4);
    float w = __expf(e);
    denom += w;
    acc.x += w * bflo(u.x);
    acc.y += w * bfhi(u.x);
    acc.z += w * bflo(u.y);
    acc.w += w * bfhi(u.y);
  }
  float inv = (deg > 0) ? 1.f / denom : 0.f;
  float4 b = *(const float4*)(bias + lane * 4);
  float4 v;
  v.x = acc.x * inv + b.x;
  v.y = acc.y * inv + b.y;
  v.z = acc.z * inv + b.z;
  v.w = acc.w * inv + b.w;
  v.x = v.x > 0.f ? v.x : expm1f(v.x);
  v.y = v.y > 0.f ? v.y : expm1f(v.y);
  v.z = v.z > 0.f ? v.z : expm1f(v.z);
  v.w = v.w > 0.f ? v.w : expm1f(v.w);
  uint2 o;
  o.x = pack2(v.x, v.y);
  o.y = pack2(v.z, v.w);
  *(uint2*)(h1 + (size_t)node * 256 + lane * 4) = o;
}

// ---------- layer-2 softmax (no-max) + aggregate + residual ----------
__launch_bounds__(256)
__global__ void agg2_k(const int* __restrict__ ell, const int* __restrict__ cnt,
                       const float* __restrict__ el, const float* __restrict__ er,
                       const short* __restrict__ ft, float* __restrict__ out) {
  int node = blockIdx.x * 4 + (threadIdx.x >> 6);
  int lane = threadIdx.x & 63;
  if (node >= N_NODES) return;
  int deg = min(cnt[node], ELL_W);
  const int* row = ell + (size_t)node * ELL_W;
  float erd = er[node];
  float denom = 0.f, acc = 0.f;
  int i = 0;
  for (; i + 8 <= deg; i += 8) {
    int s[8];
#pragma unroll
    for (int k = 0; k < 8; ++k) s[k] = row[i + k];
    float e[8], f[8];
#pragma unroll
    for (int k = 0; k < 8; ++k) e[k] = leaky(el[s[k]] + erd);
#pragma unroll
    for (int k = 0; k < 8; ++k)
      f[k] = bflo((unsigned)(unsigned short)ft[(size_t)s[k] * 64 + lane]);
#pragma unroll
    for (int k = 0; k < 8; ++k) {
      float w = __expf(e[k]);
      denom += w;
      acc += w * f[k];
    }
  }
  for (; i < deg; ++i) {
    int s = row[i];
    float e = leaky(el[s] + erd);
    float f = bflo((unsigned)(unsigned short)ft[(size_t)s * 64 + lane]);
    float w = __expf(e);
    denom += w;
    acc += w * f;
  }
  float r = (deg > 0) ? acc / denom : 0.f;
  out[(size_t)node * 64 + lane] += r;
}

// ---------- launch ----------
extern "C" void kernel_launch(void* const* d_in, const int* in_sizes, int n_in,
                              void* d_out, int out_size, void* d_ws, size_t ws_size,
                              hipStream_t stream) {
  const float* feat  = (const float*)d_in[0];
  const int*   src   = (const int*)d_in[1];
  const int*   dst   = (const int*)d_in[2];
  const float* W1    = (const float*)d_in[3];
  const float* al1   = (const float*)d_in[4];
  const float* ar1   = (const float*)d_in[5];
  const float* b1    = (const float*)d_in[6];
  const float* W2    = (const float*)d_in[7];
  const float* al2   = (const float*)d_in[8];
  const float* ar2   = (const float*)d_in[9];
  const float* b2    = (const float*)d_in[10];
  const float* resW2 = (const float*)d_in[11];
  float* out = (float*)d_out;

  char* p = (char*)d_ws;
  short* ft1b = (short*)p; p += (size_t)N_NODES * 256 * 2;
  short* h1b  = (short*)p; p += (size_t)N_NODES * 256 * 2;
  short* ft2b = (short*)p; p += (size_t)N_NODES * 64 * 2;
  short* Wt1  = (short*)p; p += 256 * 256 * 2;
  short* Wt2  = (short*)p; p += 128 * 256 * 2;
  float* el1  = (float*)p; p += (size_t)N_NODES * 4 * 4;
  float* er1  = (float*)p; p += (size_t)N_NODES * 4 * 4;
  float* el2  = (float*)p; p += (size_t)N_NODES * 4;
  float* er2  = (float*)p; p += (size_t)N_NODES * 4;
  int* cnt    = (int*)p;   p += (size_t)N_NODES * 4;
  unsigned char* slot8 = (unsigned char*)p; p += (size_t)N_EDGES;
  int* ell    = (int*)p;   // 50000*64*4 = 12.8MB

  hipMemsetAsync(cnt, 0, (size_t)N_NODES * sizeof(int), stream);

  dim3 blk(256);

  // prep: weight packs + per-edge slot assignment (the atomics live here)
  prep_k<<<2048, blk, 0, stream>>>(W1, W2, resW2, dst, Wt1, Wt2, cnt, slot8);

  // layer 1 GEMM (fp32 A, +fused el1/er1) with atomic-free ELL store strip (y==2)
  mfma_gemm_k<0, true><<<dim3(391, 3), blk, 0, stream>>>(
      feat, Wt1, nullptr, al1, ar1, el1, er1, ft1b, nullptr,
      src, dst, slot8, ell, N_NODES, 256, 256);
  agg1_k<<<12500, blk, 0, stream>>>(ell, cnt, el1, er1, ft1b, b1, h1b);

  // layer 2: [ft2 | res+b2] = h1 @ [W2 | resW2] + fused el2/er2
  mfma_gemm_k<1, false><<<dim3(391, 1), blk, 0, stream>>>(
      h1b, Wt2, b2, al2, ar2, el2, er2, ft2b, out,
      nullptr, nullptr, nullptr, nullptr, N_NODES, 256, 128);
  agg2_k<<<12500, blk, 0, stream>>>(ell, cnt, el2, er2, ft2b, out);
}